// Round 7
// baseline (689.194 us; speedup 1.0000x reference)
//
#include <hip/hip_runtime.h>
#include <hip/hip_bf16.h>

// Problem constants (fixed by setup_inputs)
constexpr int    TOT = 65536;        // nodes per side
constexpr int    TOT2 = 131072;      // both sides
constexpr long long Ec = 16LL * TOT; // 1048576 edges per side

typedef unsigned int   uint32;
typedef unsigned short ushort16;
typedef __attribute__((ext_vector_type(8))) short bf16x8;
typedef __attribute__((ext_vector_type(4))) float f32x4;

__device__ __forceinline__ float sigm(float x) { return 1.f / (1.f + __expf(-x)); }

// f32 -> bf16 (round-to-nearest-even), low 16 bits
__device__ __forceinline__ uint32 f2bf_rne(float x) {
    uint32 u = __float_as_uint(x);
    return (u + 0x7fffu + ((u >> 16) & 1u)) >> 16;
}
__device__ __forceinline__ float2 bf2f(uint32 u) {
    return make_float2(__uint_as_float(u << 16), __uint_as_float(u & 0xffff0000u));
}
__device__ __forceinline__ float bf1f(ushort16 u) {
    return __uint_as_float(((uint32)u) << 16);
}

// ---------------- small utility kernels ----------------
__global__ void degcnt2_k(int* __restrict__ deg, const int* __restrict__ dst1,
                          const int* __restrict__ dst2) {
    long long t = (long long)blockIdx.x * 256 + threadIdx.x;
    if (t < Ec) atomicAdd(&deg[dst1[t]], 1);
    else        atomicAdd(&deg[TOT + dst2[t - Ec]], 1);
}

__global__ void dis_k(float* __restrict__ dis, const int* __restrict__ deg) {
    int t = blockIdx.x * 256 + threadIdx.x;
    if (t < TOT2) dis[t] = rsqrtf((float)deg[t] + 1.0f);
}

// batch arrays sorted: st/cnt per (side,graph) via binary search
__global__ void bs_k(const int* __restrict__ b1, const int* __restrict__ b2,
                     int* __restrict__ cnt, int* __restrict__ st) {
    int t = threadIdx.x;
    const int* bat = (t < 128) ? b1 : b2;
    const int g = t & 127;
    int lo = 0, hi = TOT;
    while (lo < hi) { int m = (lo + hi) >> 1; if (bat[m] < g) lo = m + 1; else hi = m; }
    const int s0 = lo;
    hi = TOT;
    while (lo < hi) { int m = (lo + hi) >> 1; if (bat[m] < g + 1) lo = m + 1; else hi = m; }
    st[t] = s0;
    cnt[t] = lo - s0;
}

// Exclusive scan of degrees per side -> global rowptr + cursor copy.
__global__ __launch_bounds__(1024) void scan_side_k(const int* __restrict__ deg, int* __restrict__ rowptr,
                                                    int* __restrict__ cursor) {
    const int side = blockIdx.x;
    const int* dg = deg + side * TOT;
    __shared__ int wsum[16];
    const int t = threadIdx.x, lane = t & 63, wid = t >> 6;
    const int base = t * 64;
    int run = 0;
    for (int q = 0; q < 64; ++q) run += dg[base + q];
    int inc = run;
#pragma unroll
    for (int d = 1; d < 64; d <<= 1) { int n = __shfl_up(inc, d, 64); if (lane >= d) inc += n; }
    if (lane == 63) wsum[wid] = inc;
    __syncthreads();
    if (t == 0) { int o = 0; for (int q = 0; q < 16; ++q) { int x = wsum[q]; wsum[q] = o; o += x; } }
    __syncthreads();
    int off = wsum[wid] + inc - run + side * (int)Ec;
    int* rp = rowptr + side * TOT;
    int* cp = cursor + side * TOT;
    for (int q = 0; q < 64; ++q) { int v = dg[base + q]; rp[base + q] = off; cp[base + q] = off; off += v; }
    if (side == 1 && t == 1023) rowptr[TOT2] = off;
}

// both sides in one dispatch; src index only (weights folded into hs rows)
__global__ void csrfill2_k(const int* __restrict__ ei1, const int* __restrict__ ei2,
                           int* __restrict__ cursor, int* __restrict__ csr_src) {
    long long t = (long long)blockIdx.x * 256 + threadIdx.x;
    int s, d;
    if (t < Ec) { s = ei1[t];           d = ei1[Ec + t]; }
    else        { s = ei2[t - Ec] + TOT; d = ei2[Ec + t - Ec] + TOT; }
    int slot = atomicAdd(&cursor[d], 1);
    csr_src[slot] = s;
}

// ---------------- GEMM: out_bf16[M,NC] = dis[row] * ((relu?)X[M,K] @ W[K,NC]) ----------------
// XBF: X rows are packed bf16 (else f32). Output = hs rows (dis-scaled), packed bf16 pairs.
template<int K, int NC, bool RELU, bool XBF>
__global__ __launch_bounds__(256) void gemm_k(const void* __restrict__ X1v,
                                              const void* __restrict__ X2v,   // may equal X1v
                                              const float* __restrict__ W,
                                              const float* __restrict__ dis,
                                              uint32* __restrict__ out) {
    __shared__ float Ws[K * NC];
    const int tid = threadIdx.x;
    constexpr int WE4 = K * NC / 1024;
    {
        const float4* Wg = (const float4*)W;
        float4* Wp = (float4*)Ws;
#pragma unroll
        for (int it = 0; it < WE4; ++it) Wp[tid + it * 256] = Wg[tid + it * 256];
    }
    __syncthreads();
    const size_t row = (size_t)blockIdx.x * 256 + tid;
    float acc[NC];
#pragma unroll
    for (int j = 0; j < NC; ++j) acc[j] = 0.f;

    if (XBF) {
        const uint32* Xb = (row < TOT) ? (const uint32*)X1v + row * (K / 2)
                                       : (const uint32*)X2v + (row - TOT) * (K / 2);
        const uint4* Xr = (const uint4*)Xb;
#pragma unroll 2
        for (int k8 = 0; k8 < K / 8; ++k8) {
            uint4 xv = Xr[k8];
            float2 p0 = bf2f(xv.x), p1 = bf2f(xv.y), p2 = bf2f(xv.z), p3 = bf2f(xv.w);
            float xs[8] = {p0.x, p0.y, p1.x, p1.y, p2.x, p2.y, p3.x, p3.y};
            if (RELU) {
#pragma unroll
                for (int q = 0; q < 8; ++q) xs[q] = fmaxf(xs[q], 0.f);
            }
#pragma unroll
            for (int kk = 0; kk < 8; ++kk) {
#pragma unroll
                for (int j4 = 0; j4 < NC / 4; ++j4) {
                    float4 wv = *(const float4*)&Ws[(k8 * 8 + kk) * NC + j4 * 4];
                    acc[j4 * 4 + 0] += xs[kk] * wv.x;
                    acc[j4 * 4 + 1] += xs[kk] * wv.y;
                    acc[j4 * 4 + 2] += xs[kk] * wv.z;
                    acc[j4 * 4 + 3] += xs[kk] * wv.w;
                }
            }
        }
    } else {
        const float4* Xr = (row < TOT) ? (const float4*)((const float*)X1v + row * K)
                                       : (const float4*)((const float*)X2v + (row - TOT) * K);
#pragma unroll 2
        for (int k4 = 0; k4 < K / 4; ++k4) {
            float4 xv = Xr[k4];
            if (RELU) {
                xv.x = fmaxf(xv.x, 0.f); xv.y = fmaxf(xv.y, 0.f);
                xv.z = fmaxf(xv.z, 0.f); xv.w = fmaxf(xv.w, 0.f);
            }
            const float xs[4] = {xv.x, xv.y, xv.z, xv.w};
#pragma unroll
            for (int kk = 0; kk < 4; ++kk) {
#pragma unroll
                for (int j4 = 0; j4 < NC / 4; ++j4) {
                    float4 wv = *(const float4*)&Ws[(k4 * 4 + kk) * NC + j4 * 4];
                    acc[j4 * 4 + 0] += xs[kk] * wv.x;
                    acc[j4 * 4 + 1] += xs[kk] * wv.y;
                    acc[j4 * 4 + 2] += xs[kk] * wv.z;
                    acc[j4 * 4 + 3] += xs[kk] * wv.w;
                }
            }
        }
    }
    const float disv = dis[row];
    uint4* O4 = (uint4*)(out + row * (NC / 2));
#pragma unroll
    for (int j8 = 0; j8 < NC / 8; ++j8) {
        uint4 v;
        v.x = f2bf_rne(acc[j8 * 8 + 0] * disv) | (f2bf_rne(acc[j8 * 8 + 1] * disv) << 16);
        v.y = f2bf_rne(acc[j8 * 8 + 2] * disv) | (f2bf_rne(acc[j8 * 8 + 3] * disv) << 16);
        v.z = f2bf_rne(acc[j8 * 8 + 4] * disv) | (f2bf_rne(acc[j8 * 8 + 5] * disv) << 16);
        v.w = f2bf_rne(acc[j8 * 8 + 6] * disv) | (f2bf_rne(acc[j8 * 8 + 7] * disv) << 16);
        O4[j8] = v;
    }
}

// ---------------- GCN aggregation: unweighted CSR sum of hs rows ----------------
// out_bf16[i] = dis[i] * (hs[i] + sum_e hs[csr_src[e]]) + bias
template<int NC>
__global__ __launch_bounds__(256) void gatherb_k(uint32* __restrict__ out, const uint32* __restrict__ hs,
                                                 const float* __restrict__ dis, const float* __restrict__ bias,
                                                 const int* __restrict__ rowptr, const int* __restrict__ csr_src) {
    constexpr int TPN = NC / 2;
    constexpr int NPB = 256 / TPN;
    const int tid = threadIdx.x;
    const int cp = tid & (TPN - 1);
    const int node = blockIdx.x * NPB + tid / TPN;
    const float2 bb = ((const float2*)bias)[cp];
    float2 sv = bf2f(hs[(size_t)node * TPN + cp]);
    float acc0 = sv.x, acc1 = sv.y;
    int e = rowptr[node];
    const int e1 = rowptr[node + 1];
    for (; e + 1 < e1; e += 2) {
        int s0 = csr_src[e], s1 = csr_src[e + 1];
        float2 f0 = bf2f(hs[(size_t)s0 * TPN + cp]);
        float2 f1 = bf2f(hs[(size_t)s1 * TPN + cp]);
        acc0 += f0.x + f1.x;
        acc1 += f0.y + f1.y;
    }
    if (e < e1) {
        float2 f0 = bf2f(hs[(size_t)csr_src[e] * TPN + cp]);
        acc0 += f0.x; acc1 += f0.y;
    }
    const float dv = dis[node];
    out[(size_t)node * TPN + cp] = f2bf_rne(acc0 * dv + bb.x) | (f2bf_rne(acc1 * dv + bb.y) << 16);
}

// ---------------- attention pooling (bf16 AF input) ----------------
__global__ __launch_bounds__(256) void attpool_k(const ushort16* __restrict__ af,
                                                 const int* __restrict__ cnt, const int* __restrict__ st,
                                                 const float* __restrict__ attW, float* __restrict__ pool) {
    const int side = blockIdx.x >> 7, b = blockIdx.x & 127;
    const ushort16* h = af + (size_t)side * TOT * 32;
    const int c = cnt[side * 128 + b], s0 = st[side * 128 + b];
    const int f = threadIdx.x & 31, grp = threadIdx.x >> 5;
    __shared__ float red[8][32];
    __shared__ float mhS[32], tS[32];
    float acc = 0.f;
    for (int i = grp; i < c; i += 8) acc += bf1f(h[(size_t)(s0 + i) * 32 + f]);
    red[grp][f] = acc;
    __syncthreads();
    if (threadIdx.x < 32) { float tt = 0; for (int g = 0; g < 8; ++g) tt += red[g][f]; mhS[f] = tt / (float)c; }
    __syncthreads();
    if (threadIdx.x < 32) {
        float g = 0;
        for (int k = 0; k < 32; ++k) g += mhS[k] * attW[k * 32 + f];
        tS[f] = tanhf(g);
    }
    __syncthreads();
    const float tf = tS[f];
    acc = 0.f;
    for (int i = grp; i < c; i += 8) {
        float hv = bf1f(h[(size_t)(s0 + i) * 32 + f]);
        float pr = hv * tf;
#pragma unroll
        for (int m = 16; m; m >>= 1) pr += __shfl_xor(pr, m, 32);
        float sA = 1.f / (1.f + expf(-pr));
        acc += hv * sA;
    }
    __syncthreads();
    red[grp][f] = acc;
    __syncthreads();
    if (threadIdx.x < 32) {
        float tt = 0; for (int g = 0; g < 8; ++g) tt += red[g][f];
        pool[(size_t)(side * 128 + b) * 32 + f] = tt;
    }
}

// ---------------- histogram pass 1: MFMA min/max of raw dots ----------------
__global__ __launch_bounds__(256) void mm2_k(const ushort16* __restrict__ afb,
                                             const int* __restrict__ cnt, const int* __restrict__ st,
                                             float* __restrict__ bmn, float* __restrict__ bmx) {
    const int b = blockIdx.x >> 3, it8 = blockIdx.x & 7;
    const int c1 = cnt[b], c2 = cnt[128 + b];
    const int s1 = st[b], s2 = st[128 + b];
    const int nn = max(c1, c2);
    const int tid = threadIdx.x, lane = tid & 63, wave = tid >> 6;
    const int itile = it8 * 4 + wave;
    const int i0 = itile * 16;
    float lmn = 1e30f, lmx = -1e30f;
    if (i0 < nn) {
        const int arow = i0 + (lane & 15);
        const int koff = (lane >> 4) * 8;
        bf16x8 a = {0, 0, 0, 0, 0, 0, 0, 0};
        if (arow < c1) a = *(const bf16x8*)(afb + (size_t)(s1 + arow) * 32 + koff);
        const int ibase = i0 + (lane >> 4) * 4;
        const int njt = (nn + 15) >> 4;
        for (int jt = 0; jt < njt; ++jt) {
            const int brow = jt * 16 + (lane & 15);
            bf16x8 bb = {0, 0, 0, 0, 0, 0, 0, 0};
            if (brow < c2) bb = *(const bf16x8*)(afb + (size_t)(s2 + brow) * 32 + koff);
            f32x4 cc = {0.f, 0.f, 0.f, 0.f};
            cc = __builtin_amdgcn_mfma_f32_16x16x32_bf16(a, bb, cc, 0, 0, 0);
            if (brow < nn) {
#pragma unroll
                for (int r = 0; r < 4; ++r) {
                    if (ibase + r < nn) { lmn = fminf(lmn, cc[r]); lmx = fmaxf(lmx, cc[r]); }
                }
            }
        }
    }
    __shared__ float redn[256], redx[256];
    redn[tid] = lmn; redx[tid] = lmx;
    __syncthreads();
    for (int sr = 128; sr; sr >>= 1) {
        if (tid < sr) {
            redn[tid] = fminf(redn[tid], redn[tid + sr]);
            redx[tid] = fmaxf(redx[tid], redx[tid + sr]);
        }
        __syncthreads();
    }
    if (tid == 0) { bmn[blockIdx.x] = redn[0]; bmx[blockIdx.x] = redx[0]; }
}

// ---------------- histogram pass 2: MFMA + bin ----------------
__global__ __launch_bounds__(256) void bin2_k(const ushort16* __restrict__ afb,
                                              const int* __restrict__ cnt, const int* __restrict__ st,
                                              const float* __restrict__ bmn, const float* __restrict__ bmx,
                                              float* __restrict__ hist) {
    const int b = blockIdx.x >> 3, it8 = blockIdx.x & 7;
    const int c1 = cnt[b], c2 = cnt[128 + b];
    const int s1 = st[b], s2 = st[128 + b];
    const int nn = max(c1, c2);
    const int tid = threadIdx.x, lane = tid & 63, wave = tid >> 6;
    const int itile = it8 * 4 + wave;
    const int i0 = itile * 16;
    float dmn = 1e30f, dmx = -1e30f;
#pragma unroll
    for (int q = 0; q < 8; ++q) {
        dmn = fminf(dmn, bmn[(b << 3) + q]);
        dmx = fmaxf(dmx, bmx[(b << 3) + q]);
    }
    const float vMn = sigm(dmn), vMx = sigm(dmx);
    const float vScale = 16.f / ((vMx > vMn) ? (vMx - vMn) : 1.f);
    __shared__ int hloc[16 * 256];
    __shared__ int part[64];
#pragma unroll
    for (int q = 0; q < 16; ++q) hloc[q * 256 + tid] = 0;
    __syncthreads();
    if (i0 < nn) {
        const int arow = i0 + (lane & 15);
        const int koff = (lane >> 4) * 8;
        bf16x8 a = {0, 0, 0, 0, 0, 0, 0, 0};
        if (arow < c1) a = *(const bf16x8*)(afb + (size_t)(s1 + arow) * 32 + koff);
        const int ibase = i0 + (lane >> 4) * 4;
        const int njt = (nn + 15) >> 4;
        for (int jt = 0; jt < njt; ++jt) {
            const int brow = jt * 16 + (lane & 15);
            bf16x8 bb = {0, 0, 0, 0, 0, 0, 0, 0};
            if (brow < c2) bb = *(const bf16x8*)(afb + (size_t)(s2 + brow) * 32 + koff);
            f32x4 cc = {0.f, 0.f, 0.f, 0.f};
            cc = __builtin_amdgcn_mfma_f32_16x16x32_bf16(a, bb, cc, 0, 0, 0);
            if (brow < nn) {
#pragma unroll
                for (int r = 0; r < 4; ++r) {
                    if (ibase + r < nn) {
                        float t = (sigm(cc[r]) - vMn) * vScale;
                        int bi = (int)floorf(t);
                        bi = bi < 0 ? 0 : (bi > 15 ? 15 : bi);
                        hloc[bi * 256 + tid] += 1;
                    }
                }
            }
        }
    }
    __syncthreads();
    if (tid < 64) {
        const int bin = tid & 15, q = tid >> 4;
        int s = 0;
        for (int t2 = q * 64; t2 < q * 64 + 64; ++t2) s += hloc[bin * 256 + t2];
        part[tid] = s;
    }
    __syncthreads();
    if (tid < 16) {
        int s = part[tid] + part[16 + tid] + part[32 + tid] + part[48 + tid];
        atomicAdd(&hist[b * 16 + tid], (float)s);
    }
}

// ---------------- NTN + final MLP (one block per graph) ----------------
__global__ __launch_bounds__(64) void final_k(const float* __restrict__ pool, const float* __restrict__ hist,
                                              const int* __restrict__ cnt,
                                              const float* __restrict__ ntnW, const float* __restrict__ ntnV,
                                              const float* __restrict__ ntnb, const float* __restrict__ fc1W,
                                              const float* __restrict__ fc1b, const float* __restrict__ scW,
                                              const float* __restrict__ scb, float* __restrict__ out) {
    const int b = blockIdx.x;
    const int tid = threadIdx.x;
    __shared__ float P1[32], P2[32], feat[32], red[64];
    if (tid < 32) { P1[tid] = pool[b * 32 + tid]; P2[tid] = pool[4096 + b * 32 + tid]; }
    __syncthreads();
    const int k = tid & 15, part = tid >> 4;
    float acc = 0.f;
    for (int i = part * 8; i < part * 8 + 8; ++i) {
        float p1i = P1[i];
        for (int j = 0; j < 32; ++j) acc += p1i * P2[j] * ntnW[(i * 32 + j) * 16 + k];
    }
    red[tid] = acc;
    __syncthreads();
    if (tid < 16) {
        float bl = red[tid] + red[16 + tid] + red[32 + tid] + red[48 + tid];
        float blk = ntnb[tid];
        for (int i = 0; i < 32; ++i) blk += P1[i] * ntnV[tid * 64 + i];
        for (int j = 0; j < 32; ++j) blk += P2[j] * ntnV[tid * 64 + 32 + j];
        feat[tid] = fmaxf(bl + blk, 0.f);
        const int nn = max(cnt[b], cnt[128 + b]);
        feat[16 + tid] = hist[b * 16 + tid] / (float)(nn * nn);
    }
    __syncthreads();
    if (tid < 16) {
        float h = fc1b[tid];
        for (int f = 0; f < 32; ++f) h += feat[f] * fc1W[f * 16 + tid];
        red[tid] = fmaxf(h, 0.f);
    }
    __syncthreads();
    if (tid == 0) {
        float o = scb[0];
        for (int j = 0; j < 16; ++j) o += red[j] * scW[j];
        out[b] = 1.f / (1.f + expf(-o));
    }
}

// ---------------- launch ----------------
extern "C" void kernel_launch(void* const* d_in, const int* in_sizes, int n_in,
                              void* d_out, int out_size, void* d_ws, size_t ws_size,
                              hipStream_t stream) {
    const float* x1   = (const float*)d_in[0];
    const float* x2   = (const float*)d_in[1];
    const int*   ei1  = (const int*)d_in[2];
    const int*   ei2  = (const int*)d_in[3];
    const int*   bat1 = (const int*)d_in[4];
    const int*   bat2 = (const int*)d_in[5];
    const float* W1   = (const float*)d_in[6];
    const float* b1   = (const float*)d_in[7];
    const float* W2   = (const float*)d_in[8];
    const float* b2   = (const float*)d_in[9];
    const float* W3   = (const float*)d_in[10];
    const float* b3   = (const float*)d_in[11];
    const float* attW = (const float*)d_in[12];
    const float* ntnW = (const float*)d_in[13];
    const float* ntnV = (const float*)d_in[14];
    const float* ntnb = (const float*)d_in[15];
    const float* fc1W = (const float*)d_in[16];
    const float* fc1b = (const float*)d_in[17];
    const float* scW  = (const float*)d_in[18];
    const float* scb  = (const float*)d_in[19];
    float* out = (float*)d_out;

    // workspace layout (~53 MB), all intermediate features bf16-packed
    uint32* Hbuf  = (uint32*)d_ws;                       // hs rows: 131072*32 u32 (16.8 MB)
    uint32* Gb    = Hbuf + (size_t)TOT2 * 32;            // activations: 131072*32 u32 (16.8 MB)
    uint32* AFb   = Gb + (size_t)TOT2 * 32;              // AF: 131072*16 u32 (8.4 MB)
    float* dis    = (float*)(AFb + (size_t)TOT2 * 16);   // 131072
    int*   deg    = (int*)(dis + TOT2);                  // 131072
    int*   rowptr = deg + TOT2;                          // 131073
    int*   cursor = rowptr + TOT2 + 1;                   // 131072
    int*   csrs   = cursor + TOT2;                       // 2*1048576 (8.4 MB)
    int*   cnt    = csrs + 2 * (size_t)Ec;               // 256
    int*   st     = cnt + 256;                           // 256
    float* pool   = (float*)(st + 256);                  // 8192
    float* hist   = pool + 8192;                         // 2048
    float* bmn    = hist + 2048;                         // 1024
    float* bmx    = bmn + 1024;                          // 1024

    hipMemsetAsync(deg, 0, TOT2 * sizeof(int), stream);
    hipMemsetAsync(hist, 0, 2048 * sizeof(float), stream);
    degcnt2_k<<<8192, 256, 0, stream>>>(deg, ei1 + Ec, ei2 + Ec);   // dst = ei[1]
    bs_k<<<1, 256, 0, stream>>>(bat1, bat2, cnt, st);
    dis_k<<<512, 256, 0, stream>>>(dis, deg);
    scan_side_k<<<2, 1024, 0, stream>>>(deg, rowptr, cursor);
    csrfill2_k<<<8192, 256, 0, stream>>>(ei1, ei2, cursor, csrs);

    // Layer 1 (K=128 f32 -> hs bf16)
    gemm_k<128, 64, false, false><<<512, 256, 0, stream>>>(x1, x2, W1, dis, Hbuf);
    gatherb_k<64><<<TOT2 / 8, 256, 0, stream>>>(Gb, Hbuf, dis, b1, rowptr, csrs);

    // Layer 2 (64 -> 64), relu fused into bf16 GEMM load
    gemm_k<64, 64, true, true><<<512, 256, 0, stream>>>(Gb, Gb, W2, dis, Hbuf);
    gatherb_k<64><<<TOT2 / 8, 256, 0, stream>>>(Gb, Hbuf, dis, b2, rowptr, csrs);

    // Layer 3 (64 -> 32)
    gemm_k<64, 32, true, true><<<512, 256, 0, stream>>>(Gb, Gb, W3, dis, Hbuf);
    gatherb_k<32><<<TOT2 / 16, 256, 0, stream>>>(AFb, Hbuf, dis, b3, rowptr, csrs);

    // Pooling, histogram, head
    attpool_k<<<256, 256, 0, stream>>>((const ushort16*)AFb, cnt, st, attW, pool);
    mm2_k<<<1024, 256, 0, stream>>>((const ushort16*)AFb, cnt, st, bmn, bmx);
    bin2_k<<<1024, 256, 0, stream>>>((const ushort16*)AFb, cnt, st, bmn, bmx, hist);
    final_k<<<128, 64, 0, stream>>>(pool, hist, cnt, ntnW, ntnV, ntnb, fc1W, fc1b, scW, scb, out);
}